// Round 3
// baseline (424.090 us; speedup 1.0000x reference)
//
#include <hip/hip_runtime.h>
#include <math.h>

#define VRX 100
#define NZ 80
#define GRID_CELLS (VRX*VRX*NZ)   /* 800000 */
#define NPIX (1024*1024)
#define MC 960
#define MAP_ELEMS (MC*MC)

/* ws layout (floats):
   [0, 800000)        voxel grid
   [800000, 820000)   fp maps: ch0 fp_map then ch1 fp_exp, each 100x100 row-major
   [820000, 820008)   params: cth, sth, sx, sy, ca, sa
*/

__global__ void pose_kernel(const float* __restrict__ pose_obs,
                            const float* __restrict__ poses_last,
                            const int* __restrict__ elev,
                            float* __restrict__ params,
                            float* __restrict__ out_cur) {
    float th = poses_last[2] / 57.29577951308232f;
    float s = sinf(th), c = cosf(th);
    float ny = (poses_last[1] + pose_obs[0]*s) + pose_obs[1]*c;
    float nx = (poses_last[0] + pose_obs[0]*c) - pose_obs[1]*s;
    float nt = poses_last[2] + pose_obs[2]*57.29577951308232f;
    nt = fmodf(nt - 180.0f, 360.0f) + 180.0f;
    nt = fmodf(nt + 180.0f, 360.0f) - 180.0f;
    out_cur[0] = nx; out_cur[1] = ny; out_cur[2] = nt;
    out_cur[3] = nx; out_cur[4] = ny; out_cur[5] = nt;

    float spx = -((nx*100.0f)/5.0f - 480.0f)/480.0f;   /* from nx */
    float spy = -((ny*100.0f)/5.0f - 480.0f)/480.0f;   /* from ny */
    float tdeg = nt - 180.0f;
    float trad = (tdeg * (float)M_PI) / 180.0f;
    params[0] = cosf(trad);
    params[1] = sinf(trad);
    params[2] = spy;   /* x-offset of trans grid (st[:,0] = sp reversed) */
    params[3] = spx;   /* y-offset */
    double a = (double)elev[0] * (M_PI/180.0);
    params[4] = (float)cos(a);
    params[5] = (float)sin(a);
}

__global__ void splat_kernel(const float* __restrict__ depth,
                             const float* __restrict__ feat,
                             const float* __restrict__ params,
                             float* __restrict__ grid) {
    int n = blockIdx.x*blockDim.x + threadIdx.x;
    if (n >= NPIX) return;
    int i = n >> 10, j = n & 1023;
    float d = depth[n];
    float ca = params[4], sa = params[5];

    /* point cloud (f = 512 exactly in f32) */
    float X = ((float)j - 511.5f) * d / 512.0f;
    float Z = ((float)(1023 - i) - 511.5f) * d / 512.0f;
    float Y = d;

    /* Rx(elev), +AGENT_H on z */
    float x1 = X;
    float y1 = ca*Y - sa*Z;
    float z1 = (sa*Y + ca*Z) + 88.0f;

    /* Rz(-pi/2): cb = cos(-pi/2) as f32, -sb = 1, sb = -1 */
    const float CB = 6.123233995736766e-17f;
    float x2 = (CB*x1 + y1) + 250.0f;   /* + SHIFT_X */
    float y2 = (-x1) + CB*y1;
    float z2 = z1;

    /* coords -> splat positions, matching reference op order */
    float cx = (x2/5.0f - 50.0f)/100.0f*2.0f;
    float cy = (y2/5.0f - 50.0f)/100.0f*2.0f;
    float cz = (z2/5.0f - 32.0f)/80.0f*2.0f;
    float posv[3];
    posv[0] = cx*50.0f + 50.0f;
    posv[1] = cy*50.0f + 50.0f;
    posv[2] = cz*40.0f + 40.0f;
    const float dimv[3] = {100.0f, 100.0f, 80.0f};

    int   pi[3][2];
    float wv[3][2];
#pragma unroll
    for (int dd = 0; dd < 3; ++dd) {
        float fl = floorf(posv[dd]);
#pragma unroll
        for (int o = 0; o < 2; ++o) {
            float p = fl + (float)o;
            bool safe = (p > 0.0f) && (p < dimv[dd]);
            wv[dd][o] = safe ? (1.0f - fabsf(posv[dd] - p)) : 0.0f;
            pi[dd][o] = safe ? (int)p : 0;
        }
    }
    float fv = feat[n];
#pragma unroll
    for (int c0 = 0; c0 < 2; ++c0)
#pragma unroll
    for (int c1 = 0; c1 < 2; ++c1)
#pragma unroll
    for (int c2 = 0; c2 < 2; ++c2) {
        float w = (wv[0][c0]*wv[1][c1])*wv[2][c2];
        if (w != 0.0f) {
            int idx = (pi[0][c0]*100 + pi[1][c1])*80 + pi[2][c2];
            atomicAdd(&grid[idx], fv*w);
        }
    }
}

__global__ void reduce_kernel(const float* __restrict__ grid,
                              float* __restrict__ fp,
                              float* __restrict__ out_fpmap) {
    int t = blockIdx.x*blockDim.x + threadIdx.x;
    if (t >= 10000) return;
    int r = t / 100, cc = t % 100;
    const float* g = grid + (cc*100 + (99 - r))*80;
    float s_all = 0.0f, s_mid = 0.0f;
    for (int k = 0; k < 80; ++k) {
        float v = rintf(g[k]);          /* jnp.round = half-to-even */
        s_all += v;
        if (k >= 13 && k < 25) s_mid += v;
    }
    float fpm = fminf(fmaxf(s_mid, 0.0f), 1.0f);
    float fpe = fminf(fmaxf(s_all, 0.0f), 1.0f);
    fp[t] = fpm;
    fp[10000 + t] = fpe;
    out_fpmap[t] = fpm;
}

__device__ __forceinline__ float av_at(const float* __restrict__ fp, int c, int yy, int xx) {
    if (yy >= 380 && yy < 480 && xx >= 430 && xx < 530)
        return fp[c*10000 + (yy-380)*100 + (xx-430)];
    return 0.0f;
}

__device__ __forceinline__ float samp_av(const float* __restrict__ fp, int c,
                                         float ixf, float iyf) {
    if (ixf >= 0.0f && ixf < 960.0f && iyf >= 0.0f && iyf < 960.0f)
        return av_at(fp, c, (int)iyf, (int)ixf);
    return 0.0f;
}

/* value of tmp = grid_sample(av, rot_g) at integer pixel (ii, jj), channel c */
__device__ float rot_sample(const float* __restrict__ fp, int c, int ii, int jj,
                            float cth, float sth) {
    float gxx = ((float)jj*2.0f + 1.0f)/960.0f - 1.0f;
    float gyy = ((float)ii*2.0f + 1.0f)/960.0f - 1.0f;
    float rx = cth*gxx + (-sth)*gyy;
    float ry = sth*gxx + cth*gyy;
    float x = (rx + 1.0f)*0.5f*959.0f;
    float y = (ry + 1.0f)*0.5f*959.0f;
    float x0 = floorf(x), y0 = floorf(y);
    float wx = x - x0, wy = y - y0;
    float acc;
    acc =       samp_av(fp,c,x0,     y0     )*(1.0f-wx)*(1.0f-wy);
    acc = acc + samp_av(fp,c,x0+1.0f,y0     )*wx       *(1.0f-wy);
    acc = acc + samp_av(fp,c,x0,     y0+1.0f)*(1.0f-wx)*wy;
    acc = acc + samp_av(fp,c,x0+1.0f,y0+1.0f)*wx       *wy;
    return acc;
}

__device__ __forceinline__ float samp_rot(const float* __restrict__ fp, int c,
                                          float ixf, float iyf, float cth, float sth) {
    if (ixf >= 0.0f && ixf < 960.0f && iyf >= 0.0f && iyf < 960.0f)
        return rot_sample(fp, c, (int)iyf, (int)ixf, cth, sth);
    return 0.0f;
}

__global__ void trans_kernel(const float* __restrict__ fp,
                             const float* __restrict__ params,
                             const float* __restrict__ maps_last,
                             float* __restrict__ out_map) {
    int t = blockIdx.x*blockDim.x + threadIdx.x;
    if (t >= 2*MAP_ELEMS) return;
    int c = t / MAP_ELEMS;
    int rem = t - c*MAP_ELEMS;
    int i = rem / MC, j = rem - (rem / MC)*MC;
    float cth = params[0], sth = params[1], sx = params[2], sy = params[3];

    float gx = ((float)j*2.0f + 1.0f)/960.0f - 1.0f;
    float gy = ((float)i*2.0f + 1.0f)/960.0f - 1.0f;
    float tx = gx + sx;
    float ty = gy + sy;
    float x = (tx + 1.0f)*0.5f*959.0f;
    float y = (ty + 1.0f)*0.5f*959.0f;
    float x0 = floorf(x), y0 = floorf(y);
    float wx = x - x0, wy = y - y0;
    float acc;
    acc =       samp_rot(fp,c,x0,     y0,     cth,sth)*(1.0f-wx)*(1.0f-wy);
    acc = acc + samp_rot(fp,c,x0+1.0f,y0,     cth,sth)*wx       *(1.0f-wy);
    acc = acc + samp_rot(fp,c,x0,     y0+1.0f,cth,sth)*(1.0f-wx)*wy;
    acc = acc + samp_rot(fp,c,x0+1.0f,y0+1.0f,cth,sth)*wx       *wy;

    out_map[t] = fmaxf(maps_last[t], acc);
}

extern "C" void kernel_launch(void* const* d_in, const int* in_sizes, int n_in,
                              void* d_out, int out_size, void* d_ws, size_t ws_size,
                              hipStream_t stream) {
    const float* depth      = (const float*)d_in[0];
    const float* pose_obs   = (const float*)d_in[1];
    const float* maps_last  = (const float*)d_in[2];
    const float* poses_last = (const float*)d_in[3];
    const float* feat       = (const float*)d_in[4];
    const int*   elev       = (const int*)d_in[5];
    float* out = (float*)d_out;

    float* grid   = (float*)d_ws;           /* 800000 floats */
    float* fp     = grid + GRID_CELLS;      /* 20000 floats  */
    float* params = fp + 20000;             /* 8 floats      */

    hipMemsetAsync(grid, 0, GRID_CELLS*sizeof(float), stream);
    pose_kernel<<<1, 1, 0, stream>>>(pose_obs, poses_last, elev, params,
                                     out + 10000 + 2*MAP_ELEMS);
    splat_kernel<<<(NPIX+255)/256, 256, 0, stream>>>(depth, feat, params, grid);
    reduce_kernel<<<(10000+255)/256, 256, 0, stream>>>(grid, fp, out);
    trans_kernel<<<(2*MAP_ELEMS+255)/256, 256, 0, stream>>>(fp, params, maps_last,
                                                            out + 10000);
}

// Round 4
// 401.771 us; speedup vs baseline: 1.0556x; 1.0556x over previous
//
#include <hip/hip_runtime.h>
#include <math.h>

#define VRX 100
#define NZ 80
#define GRID_CELLS (VRX*VRX*NZ)   /* 800000 */
#define NPIX (1024*1024)
#define MC 960
#define MAP_ELEMS (MC*MC)
#define RMAX 8

/* ws layout (floats):
   [0, 20000)      fp maps: ch0 fp_map then ch1 fp_exp, each 100x100 row-major
   [20000, 20008)  params: cth, sth, sx, sy, ca, sa
   [20032, ...)    R replicas of the 800000-float voxel grid
*/

__global__ void pose_kernel(const float* __restrict__ pose_obs,
                            const float* __restrict__ poses_last,
                            const int* __restrict__ elev,
                            float* __restrict__ params,
                            float* __restrict__ out_cur) {
    float th = poses_last[2] / 57.29577951308232f;
    float s = sinf(th), c = cosf(th);
    float ny = (poses_last[1] + pose_obs[0]*s) + pose_obs[1]*c;
    float nx = (poses_last[0] + pose_obs[0]*c) - pose_obs[1]*s;
    float nt = poses_last[2] + pose_obs[2]*57.29577951308232f;
    nt = fmodf(nt - 180.0f, 360.0f) + 180.0f;
    nt = fmodf(nt + 180.0f, 360.0f) - 180.0f;
    out_cur[0] = nx; out_cur[1] = ny; out_cur[2] = nt;
    out_cur[3] = nx; out_cur[4] = ny; out_cur[5] = nt;

    float spx = -((nx*100.0f)/5.0f - 480.0f)/480.0f;
    float spy = -((ny*100.0f)/5.0f - 480.0f)/480.0f;
    float tdeg = nt - 180.0f;
    float trad = (tdeg * (float)M_PI) / 180.0f;
    params[0] = cosf(trad);
    params[1] = sinf(trad);
    params[2] = spy;   /* x-offset of trans grid (st[:,0] = sp reversed) */
    params[3] = spx;   /* y-offset */
    double a = (double)elev[0] * (M_PI/180.0);
    params[4] = (float)cos(a);
    params[5] = (float)sin(a);
}

__global__ void splat_kernel(const float* __restrict__ depth,
                             const float* __restrict__ feat,
                             const float* __restrict__ params,
                             float* __restrict__ grids, int rmask) {
    int n = blockIdx.x*blockDim.x + threadIdx.x;
    if (n >= NPIX) return;
    float* grid = grids + (size_t)(blockIdx.x & rmask) * GRID_CELLS;
    int i = n >> 10, j = n & 1023;
    float d = depth[n];
    float ca = params[4], sa = params[5];

    /* point cloud (f = 512 exactly in f32) */
    float X = ((float)j - 511.5f) * d / 512.0f;
    float Z = ((float)(1023 - i) - 511.5f) * d / 512.0f;
    float Y = d;

    /* Rx(elev), +AGENT_H on z */
    float x1 = X;
    float y1 = ca*Y - sa*Z;
    float z1 = (sa*Y + ca*Z) + 88.0f;

    /* Rz(-pi/2): cb = cos(-pi/2) as f32, -sb = 1, sb = -1 */
    const float CB = 6.123233995736766e-17f;
    float x2 = (CB*x1 + y1) + 250.0f;   /* + SHIFT_X */
    float y2 = (-x1) + CB*y1;
    float z2 = z1;

    /* coords -> splat positions, matching reference op order */
    float cx = (x2/5.0f - 50.0f)/100.0f*2.0f;
    float cy = (y2/5.0f - 50.0f)/100.0f*2.0f;
    float cz = (z2/5.0f - 32.0f)/80.0f*2.0f;
    float posv[3];
    posv[0] = cx*50.0f + 50.0f;
    posv[1] = cy*50.0f + 50.0f;
    posv[2] = cz*40.0f + 40.0f;
    const float dimv[3] = {100.0f, 100.0f, 80.0f};

    int   pi[3][2];
    float wv[3][2];
#pragma unroll
    for (int dd = 0; dd < 3; ++dd) {
        float fl = floorf(posv[dd]);
#pragma unroll
        for (int o = 0; o < 2; ++o) {
            float p = fl + (float)o;
            bool safe = (p > 0.0f) && (p < dimv[dd]);
            wv[dd][o] = safe ? (1.0f - fabsf(posv[dd] - p)) : 0.0f;
            pi[dd][o] = safe ? (int)p : 0;
        }
    }
    float fv = feat[n];
#pragma unroll
    for (int c0 = 0; c0 < 2; ++c0)
#pragma unroll
    for (int c1 = 0; c1 < 2; ++c1)
#pragma unroll
    for (int c2 = 0; c2 < 2; ++c2) {
        float w = (wv[0][c0]*wv[1][c1])*wv[2][c2];
        if (w != 0.0f) {
            int idx = (pi[0][c0]*100 + pi[1][c1])*80 + pi[2][c2];
            atomicAdd(&grid[idx], fv*w);
        }
    }
}

__global__ void reduce_kernel(const float* __restrict__ grids, int R,
                              float* __restrict__ fp,
                              float* __restrict__ out_fpmap) {
    int t = blockIdx.x*blockDim.x + threadIdx.x;
    if (t >= 10000) return;
    int r = t / 100, cc = t % 100;
    size_t base = (size_t)(cc*100 + (99 - r))*80;
    float s_all = 0.0f, s_mid = 0.0f;
    for (int k = 0; k < 80; ++k) {
        float tot = 0.0f;
        for (int rep = 0; rep < R; ++rep)
            tot += grids[(size_t)rep*GRID_CELLS + base + k];
        float v = rintf(tot);           /* jnp.round = half-to-even */
        s_all += v;
        if (k >= 13 && k < 25) s_mid += v;
    }
    float fpm = fminf(fmaxf(s_mid, 0.0f), 1.0f);
    float fpe = fminf(fmaxf(s_all, 0.0f), 1.0f);
    fp[t] = fpm;
    fp[10000 + t] = fpe;
    out_fpmap[t] = fpm;
}

__device__ __forceinline__ float av_at(const float* __restrict__ fp, int c, int yy, int xx) {
    if (yy >= 380 && yy < 480 && xx >= 430 && xx < 530)
        return fp[c*10000 + (yy-380)*100 + (xx-430)];
    return 0.0f;
}

__device__ __forceinline__ float samp_av(const float* __restrict__ fp, int c,
                                         float ixf, float iyf) {
    if (ixf >= 0.0f && ixf < 960.0f && iyf >= 0.0f && iyf < 960.0f)
        return av_at(fp, c, (int)iyf, (int)ixf);
    return 0.0f;
}

/* value of tmp = grid_sample(av, rot_g) at integer pixel (ii, jj), channel c */
__device__ float rot_sample(const float* __restrict__ fp, int c, int ii, int jj,
                            float cth, float sth) {
    float gxx = ((float)jj*2.0f + 1.0f)/960.0f - 1.0f;
    float gyy = ((float)ii*2.0f + 1.0f)/960.0f - 1.0f;
    float rx = cth*gxx + (-sth)*gyy;
    float ry = sth*gxx + cth*gyy;
    float x = (rx + 1.0f)*0.5f*959.0f;
    float y = (ry + 1.0f)*0.5f*959.0f;
    float x0 = floorf(x), y0 = floorf(y);
    float wx = x - x0, wy = y - y0;
    float acc;
    acc =       samp_av(fp,c,x0,     y0     )*(1.0f-wx)*(1.0f-wy);
    acc = acc + samp_av(fp,c,x0+1.0f,y0     )*wx       *(1.0f-wy);
    acc = acc + samp_av(fp,c,x0,     y0+1.0f)*(1.0f-wx)*wy;
    acc = acc + samp_av(fp,c,x0+1.0f,y0+1.0f)*wx       *wy;
    return acc;
}

__device__ __forceinline__ float samp_rot(const float* __restrict__ fp, int c,
                                          float ixf, float iyf, float cth, float sth) {
    if (ixf >= 0.0f && ixf < 960.0f && iyf >= 0.0f && iyf < 960.0f)
        return rot_sample(fp, c, (int)iyf, (int)ixf, cth, sth);
    return 0.0f;
}

__global__ void trans_kernel(const float* __restrict__ fp,
                             const float* __restrict__ params,
                             const float* __restrict__ maps_last,
                             float* __restrict__ out_map) {
    int t = blockIdx.x*blockDim.x + threadIdx.x;
    if (t >= 2*MAP_ELEMS) return;
    int c = t / MAP_ELEMS;
    int rem = t - c*MAP_ELEMS;
    int i = rem / MC, j = rem - (rem / MC)*MC;
    float cth = params[0], sth = params[1], sx = params[2], sy = params[3];

    float gx = ((float)j*2.0f + 1.0f)/960.0f - 1.0f;
    float gy = ((float)i*2.0f + 1.0f)/960.0f - 1.0f;
    float tx = gx + sx;
    float ty = gy + sy;
    float x = (tx + 1.0f)*0.5f*959.0f;
    float y = (ty + 1.0f)*0.5f*959.0f;
    float x0 = floorf(x), y0 = floorf(y);
    float wx = x - x0, wy = y - y0;
    float acc;
    acc =       samp_rot(fp,c,x0,     y0,     cth,sth)*(1.0f-wx)*(1.0f-wy);
    acc = acc + samp_rot(fp,c,x0+1.0f,y0,     cth,sth)*wx       *(1.0f-wy);
    acc = acc + samp_rot(fp,c,x0,     y0+1.0f,cth,sth)*(1.0f-wx)*wy;
    acc = acc + samp_rot(fp,c,x0+1.0f,y0+1.0f,cth,sth)*wx       *wy;

    out_map[t] = fmaxf(maps_last[t], acc);
}

extern "C" void kernel_launch(void* const* d_in, const int* in_sizes, int n_in,
                              void* d_out, int out_size, void* d_ws, size_t ws_size,
                              hipStream_t stream) {
    const float* depth      = (const float*)d_in[0];
    const float* pose_obs   = (const float*)d_in[1];
    const float* maps_last  = (const float*)d_in[2];
    const float* poses_last = (const float*)d_in[3];
    const float* feat       = (const float*)d_in[4];
    const int*   elev       = (const int*)d_in[5];
    float* out = (float*)d_out;

    float* fp     = (float*)d_ws;        /* 20000 floats */
    float* params = fp + 20000;          /* 8 floats     */
    float* grids  = fp + 20032;          /* R * 800000   */

    /* largest power-of-2 replica count that fits the workspace (>=1) */
    size_t avail = ws_size / sizeof(float);
    int R = 1;
    while (R < RMAX && (size_t)20032 + (size_t)GRID_CELLS*(size_t)(R*2) <= avail)
        R *= 2;

    hipMemsetAsync(grids, 0, (size_t)R*GRID_CELLS*sizeof(float), stream);
    pose_kernel<<<1, 1, 0, stream>>>(pose_obs, poses_last, elev, params,
                                     out + 10000 + 2*MAP_ELEMS);
    splat_kernel<<<(NPIX+255)/256, 256, 0, stream>>>(depth, feat, params, grids, R-1);
    reduce_kernel<<<(10000+255)/256, 256, 0, stream>>>(grids, R, fp, out);
    trans_kernel<<<(2*MAP_ELEMS+255)/256, 256, 0, stream>>>(fp, params, maps_last,
                                                            out + 10000);
}